// Round 1
// baseline (105.192 us; speedup 1.0000x reference)
//
#include <hip/hip_runtime.h>

#define T_LEN 512
#define I_LEN 5

// DPP cross-lane read: lane l receives src from lane given by CTRL pattern.
// CTRLs used (all involutions, within 16-lane rows):
//   0xB1  quad_perm [1,0,3,2]  -> lane ^ 1
//   0x4E  quad_perm [2,3,0,1]  -> lane ^ 2
//   0x141 row_half_mirror      -> lane ^ 7
//   0x140 row_mirror           -> lane ^ 15
template<int CTRL>
__device__ __forceinline__ float fdpp(float x) {
    return __int_as_float(__builtin_amdgcn_update_dpp(
        0, __float_as_int(x), CTRL, 0xF, 0xF, true));
}

__device__ __forceinline__ float tanh_fast(float x) {
    // tanh(x) = 1 - 2/(exp(2x)+1); exp(2x) = exp2(x * 2*log2(e))
    float e = __builtin_exp2f(x * 2.8853900817779268f);
    float r = __builtin_amdgcn_rcpf(e + 1.0f);
    return __builtin_fmaf(-2.0f, r, 1.0f); // saturates to +/-1 correctly
}

__global__ __launch_bounds__(256, 2) void rnn_m2o_kernel(
    const float* __restrict__ x, const float* __restrict__ W_ih,
    const float* __restrict__ W_hh, const float* __restrict__ b_ih,
    const float* __restrict__ b_hh, const float* __restrict__ W_fc,
    const float* __restrict__ b_fc, float* __restrict__ out)
{
    const int j   = threadIdx.x & 15;   // hidden unit owned by this lane
    const int grp = threadIdx.x >> 4;   // group-of-16 within block
    const int b   = blockIdx.x * 16 + grp;  // batch element

    // Per-lane weights (broadcast loads, negligible)
    float wih[I_LEN];
#pragma unroll
    for (int i = 0; i < I_LEN; ++i) wih[i] = W_ih[j * I_LEN + i];
    const float bias = b_ih[j] + b_hh[j];

    // XOR-skewed W_hh row: whh[m] = W_hh[j][j^m], pairs with h from lane j^m
    float whh[16];
#pragma unroll
    for (int m = 0; m < 16; ++m) whh[m] = W_hh[j * 16 + (j ^ m)];

    const float wfc = W_fc[j];
    const float bfc = b_fc[0];

    const float* xb = x + (size_t)b * (T_LEN * I_LEN);

    // 4 timesteps = 20 floats = 5 float4 (16B-aligned since t%4==0)
    float4 q0, q1, q2, q3, q4;
    {
        const float4* p = reinterpret_cast<const float4*>(xb);
        q0 = p[0]; q1 = p[1]; q2 = p[2]; q3 = p[3]; q4 = p[4];
    }

    float h = 0.0f;

    for (int t = 0; t < T_LEN; t += 4) {
        // software prefetch next 4-step block (last iter harmlessly reloads)
        const int tn = (t + 4 < T_LEN) ? (t + 4) : t;
        const float4* pn = reinterpret_cast<const float4*>(xb + tn * I_LEN);
        float4 n0 = pn[0], n1 = pn[1], n2 = pn[2], n3 = pn[3], n4 = pn[4];

        const float xs[20] = {q0.x, q0.y, q0.z, q0.w,
                              q1.x, q1.y, q1.z, q1.w,
                              q2.x, q2.y, q2.z, q2.w,
                              q3.x, q3.y, q3.z, q3.w,
                              q4.x, q4.y, q4.z, q4.w};

#pragma unroll
        for (int s = 0; s < 4; ++s) {
            // input projection, split into parallel chains
            float acc0 = __builtin_fmaf(xs[5 * s + 0], wih[0], bias);
            float acc1 = xs[5 * s + 1] * wih[1];
            acc1 = __builtin_fmaf(xs[5 * s + 2], wih[2], acc1);
            float acc2 = xs[5 * s + 3] * wih[3];
            acc2 = __builtin_fmaf(xs[5 * s + 4], wih[4], acc2);

            // DPP allgather: hr[m] = h_{j^m}
            float hr[16];
            hr[0]  = h;
            hr[1]  = fdpp<0xB1>(hr[0]);
            hr[2]  = fdpp<0x4E>(hr[0]);
            hr[3]  = fdpp<0x4E>(hr[1]);
            hr[7]  = fdpp<0x141>(hr[0]);
            hr[6]  = fdpp<0x141>(hr[1]);
            hr[5]  = fdpp<0x141>(hr[2]);
            hr[4]  = fdpp<0x141>(hr[3]);
            hr[15] = fdpp<0x140>(hr[0]);
            hr[14] = fdpp<0x140>(hr[1]);
            hr[13] = fdpp<0x140>(hr[2]);
            hr[12] = fdpp<0x140>(hr[3]);
            hr[11] = fdpp<0x140>(hr[4]);
            hr[10] = fdpp<0x140>(hr[5]);
            hr[9]  = fdpp<0x140>(hr[6]);
            hr[8]  = fdpp<0x140>(hr[7]);

            // recurrent matvec: 4 parallel accumulator chains
            float a0 = acc0, a1 = acc1, a2 = acc2, a3 = 0.0f;
#pragma unroll
            for (int m = 0; m < 16; m += 4) {
                a0 = __builtin_fmaf(hr[m + 0], whh[m + 0], a0);
                a1 = __builtin_fmaf(hr[m + 1], whh[m + 1], a1);
                a2 = __builtin_fmaf(hr[m + 2], whh[m + 2], a2);
                a3 = __builtin_fmaf(hr[m + 3], whh[m + 3], a3);
            }
            h = tanh_fast((a0 + a1) + (a2 + a3));
        }

        q0 = n0; q1 = n1; q2 = n2; q3 = n3; q4 = n4;
    }

    // fc + sigmoid: reduce h_j * wfc_j over the 16-lane group via DPP
    float r = h * wfc;
    r += fdpp<0xB1>(r);   // + lane^1
    r += fdpp<0x4E>(r);   // + quad partner pair -> quad sum
    r += fdpp<0x141>(r);  // + other quad in 8-row
    r += fdpp<0x140>(r);  // + other 8-row -> full 16 sum
    if (j == 0) {
        float z = r + bfc;
        float sg = __builtin_amdgcn_rcpf(
            1.0f + __builtin_exp2f(z * -1.4426950408889634f));
        out[b] = sg;
    }
}

extern "C" void kernel_launch(void* const* d_in, const int* in_sizes, int n_in,
                              void* d_out, int out_size, void* d_ws, size_t ws_size,
                              hipStream_t stream) {
    const float* x    = (const float*)d_in[0];
    const float* W_ih = (const float*)d_in[1];
    const float* W_hh = (const float*)d_in[2];
    const float* b_ih = (const float*)d_in[3];
    const float* b_hh = (const float*)d_in[4];
    const float* W_fc = (const float*)d_in[5];
    const float* b_fc = (const float*)d_in[6];
    float* out = (float*)d_out;

    const int B = in_sizes[0] / (T_LEN * I_LEN);   // 8192
    const int blocks = B / 16;                     // 16 batch elements / block
    rnn_m2o_kernel<<<blocks, 256, 0, stream>>>(x, W_ih, W_hh, b_ih, b_hh,
                                               W_fc, b_fc, out);
}